// Round 8
// baseline (4059.906 us; speedup 1.0000x reference)
//
#include <hip/hip_runtime.h>
#include <stdint.h>

// LSTM: B=256, T=1024, I=64, H=256, O=1. fp32 in/out, bf16 MFMA internally.
//
// Round-19: same 2-half topology + phase-split pipeline as R17/R18, but
// 256-THREAD blocks. R15 (512,2)->VGPR 128 and R18 (512,1)->VGPR 128 prove
// the allocator will not give a 512-thread block more than 128 VGPRs
// (8 waves = 2 waves/SIMD caps the file at 256; heuristic lands at 128),
// so wf[4][10]=160 VGPRs spilled in EVERY round since R15 - the topology
// never ran with resident weights. 256-thread blocks = 4 waves = 1
// wave/SIMD -> cap 512 VGPRs; R11 precedent shows clean allocation at this
// block size.
//
// 64 blocks = 32 groups x 2 halves, 256 thr. Wave wv (0..3) owns hid =
// half*128 + wv*32 + {nt*16+ln : nt=0,1}, ALL 4 gates -> wf[4][2][10]
// (320 VGPRs), every index compile-time after unroll (rule-#20: slot order
// 0..1 = x | 2..5 = own-half W_hh | 6..9 = peer-half W_hh; the half-
// dependence lives only in load ADDRESSES). c/h update fully in-register.
//
// Software-pipelined recurrence: Phase A (bias + x + own-half h: 48 MFMAs)
// runs while the peer poll is in flight; only Phase C (peer-half: 32
// MFMAs) + nonlin + publish sit on the serial publish->visibility->detect
// cycle. x prefetched one step ahead (clamped at T-1).
//
// Poll: 256 threads <-> 512 peer units, each thread exactly 2 (units i and
// 256+i), both probes issued before any sleep, reloads issued BEFORE
// s_sleep(1) so MALL latency hides under it; satisfied lanes stop loading;
// SENT_CAP dead-latch => wrong-answer-not-hang. Communication primitive:
// R11/R13-verified relaxed AGENT-scope (MALL) 8B units {2xbf16 h pair,
// tag=step}. Tag poison 0xAAAAAAAA != live tags 1..1024 => no ws init.
// Final h (tag 1024) -> separate never-polled clean region at 2*UPP
// (R13-verified). Parity/staleness argument as R15.
//
// LDS: h_lds[2][8][264] double buffer. iter t: Phase A reads OWN cols of
// buf[t&1] (written by update(t-1), ordered by END-barrier(t-1)); capture
// writes PEER cols of buf[t&1] (disjoint); MID-barrier; Phase C reads peer
// cols; update writes own h(t+1) to buf[(t+1)&1] + publishes; END-barrier.

#define T_ 1024
#define I_ 64
#define H_ 256
#define NGROUP 32
#define MB 8      /* batches per group  */
#define HH 128    /* hidden units per block (half) */
#define HROW 264  /* padded h_lds row (ushorts), 528 B = 33 x 16 B */

#define UNITS_PER_GROUP 1024                       /* 8B units per step */
#define UNITS_PER_PARITY (NGROUP * UNITS_PER_GROUP)
#define SENT_CAP (1 << 16)   /* dead-latch: ~64k sleep-sweeps */

typedef float floatx4 __attribute__((ext_vector_type(4)));
typedef __bf16 bf16x8 __attribute__((ext_vector_type(8)));
typedef unsigned short ushortx8 __attribute__((ext_vector_type(8)));
typedef unsigned int uint32;
typedef unsigned long long u64;

__device__ __forceinline__ float bf2f(uint32 u16) {
  uint32 u = u16 << 16;
  return __builtin_bit_cast(float, u);
}
__device__ __forceinline__ bf16x8 packbf8(floatx4 a, floatx4 b) {
  bf16x8 r;
  r[0] = (__bf16)a[0]; r[1] = (__bf16)a[1];
  r[2] = (__bf16)a[2]; r[3] = (__bf16)a[3];
  r[4] = (__bf16)b[0]; r[5] = (__bf16)b[1];
  r[6] = (__bf16)b[2]; r[7] = (__bf16)b[3];
  return r;
}
__device__ __forceinline__ float fast_sig(float v) {
  return 1.0f / (1.0f + __expf(-v));
}
__device__ __forceinline__ float fast_tanh(float v) {
  float e = __expf(2.0f * v);
  return 1.0f - 2.0f / (e + 1.0f);
}
__device__ __forceinline__ u64 aload64(const u64* p) {
  return __hip_atomic_load(p, __ATOMIC_RELAXED, __HIP_MEMORY_SCOPE_AGENT);
}
__device__ __forceinline__ void astore64(u64* p, u64 v) {
  __hip_atomic_store(p, v, __ATOMIC_RELAXED, __HIP_MEMORY_SCOPE_AGENT);
}

__global__ __launch_bounds__(256, 1) void lstm_main(
    const float* __restrict__ x, const float* __restrict__ W_ih,
    const float* __restrict__ W_hh, const float* __restrict__ b_ih,
    const float* __restrict__ b_hh, u64* __restrict__ units) {
  const int tid = threadIdx.x;
  const int bid = blockIdx.x;
  const int half = bid >> 5;  // 0..1
  const int g = bid & 31;     // group 0..31 (bid%8 spreads XCDs)
  const int wv = tid >> 6;    // wave 0..3 -> hid sub-block (32 units)
  const int lane = tid & 63;
  const int ln = lane & 15;   // MFMA n (hid) / A row (batch, dup)
  const int lk = lane >> 4;   // MFMA k-subgroup / C row group

  __shared__ __align__(16) unsigned short h_lds[2][MB][HROW];

  const size_t gbase = (size_t)g * UNITS_PER_GROUP;
  const size_t obase = gbase + (size_t)half * 512;        // own units
  const size_t pbase = gbase + (size_t)(half ^ 1) * 512;  // peer units
  const int ownb = half * HH;                             // own col base
  const int peerb = (half ^ 1) * HH;                      // peer col base

  // zero both h_lds buffers (h_0 = 0; also clears pad)
  {
    uint32* p = (uint32*)&h_lds[0][0][0];
    for (int i = tid; i < 2 * MB * HROW / 2; i += 256) p[i] = 0u;
  }

  // ---- preload weight B-fragments (bf16) + bias, once ----
  // wave wv owns hid = half*128 + wv*32 + nt*16 + ln, ALL 4 gates (j).
  // Slot order: 0..1 x | 2..5 own-half W_hh | 6..9 peer-half W_hh.
  bf16x8 wf[4][2][10];
  float bias[4][2];
#pragma unroll
  for (int j = 0; j < 4; ++j) {
#pragma unroll
    for (int nt = 0; nt < 2; ++nt) {
      const int row = j * 256 + half * HH + wv * 32 + nt * 16 + ln;
      bias[j][nt] = b_ih[row] + b_hh[row];
      const float* wih = W_ih + (size_t)row * I_;
      const float* whh = W_hh + (size_t)row * H_;
#pragma unroll
      for (int fc = 0; fc < 10; ++fc) {
        const float* src;
        if (fc < 2)      src = wih + fc * 32 + lk * 8;
        else if (fc < 6) src = whh + ownb + (fc - 2) * 32 + lk * 8;
        else             src = whh + peerb + (fc - 6) * 32 + lk * 8;
        floatx4 f0 = *(const floatx4*)src;
        floatx4 f1 = *(const floatx4*)(src + 4);
        wf[j][nt][fc] = packbf8(f0, f1);
      }
    }
  }

  const int mb = ln & 7;                       // batch row (m>=8 duplicates)
  const float* xrow = x + ((size_t)(g * MB + mb)) * T_ * I_;
  // poll roles: thread i <-> peer units i and 256+i
  const int pm0 = tid >> 6;                    // batch of unit i (0..3)
  const int pcol = peerb + 2 * (tid & 63);     // h_lds col (ushort)
  // publish roles: active lanes lk<2 && even ln
  const int ocol = ownb + wv * 32;             // + nt*16 + ln at use
  const int opair = wv * 16 + (ln >> 1);       // + nt*8 at use

  floatx4 c0 = (floatx4){0.f, 0.f, 0.f, 0.f};
  floatx4 c1 = (floatx4){0.f, 0.f, 0.f, 0.f};

  // preload x_0
  floatx4 xf0, xf1, xf2, xf3;
  {
    const float* src = xrow + lk * 8;
    xf0 = *(const floatx4*)(src);
    xf1 = *(const floatx4*)(src + 4);
    xf2 = *(const floatx4*)(src + 32);
    xf3 = *(const floatx4*)(src + 36);
  }

  __syncthreads();

#pragma unroll 1
  for (int t = 0; t < T_; ++t) {
    // pack x_t fragments, then issue x_{t+1} prefetch (hides under Phase A)
    bf16x8 a0 = packbf8(xf0, xf1);
    bf16x8 a1 = packbf8(xf2, xf3);
    {
      const int tn = (t + 1 < T_) ? (t + 1) : t;
      const float* src = xrow + tn * I_ + lk * 8;
      xf0 = *(const floatx4*)(src);
      xf1 = *(const floatx4*)(src + 4);
      xf2 = *(const floatx4*)(src + 32);
      xf3 = *(const floatx4*)(src + 36);
    }

    // issue both poll probes BEFORE Phase A so they fly under the MFMAs
    u64* up0 = units + (size_t)(t & 1) * UNITS_PER_PARITY + pbase + tid;
    u64* up1 = up0 + 256;
    u64 v0 = 0, v1 = 0;
    if (t > 0) {
      v0 = aload64(up0);
      v1 = aload64(up1);
    }

    // ---- Phase A: bias + x-part + OWN-half h (local, from buf[t&1]) ----
    const unsigned short* hrow = &h_lds[t & 1][mb][0];
    floatx4 acc[4][2];
#pragma unroll
    for (int j = 0; j < 4; ++j)
#pragma unroll
      for (int nt = 0; nt < 2; ++nt)
        acc[j][nt] =
            (floatx4){bias[j][nt], bias[j][nt], bias[j][nt], bias[j][nt]};
#pragma unroll
    for (int j = 0; j < 4; ++j) {
#pragma unroll
      for (int nt = 0; nt < 2; ++nt) {
        acc[j][nt] = __builtin_amdgcn_mfma_f32_16x16x32_bf16(
            a0, wf[j][nt][0], acc[j][nt], 0, 0, 0);
        acc[j][nt] = __builtin_amdgcn_mfma_f32_16x16x32_bf16(
            a1, wf[j][nt][1], acc[j][nt], 0, 0, 0);
      }
    }
#pragma unroll
    for (int kk = 0; kk < 4; ++kk) {
      bf16x8 a = __builtin_bit_cast(
          bf16x8, *(const ushortx8*)(hrow + ownb + kk * 32 + lk * 8));
#pragma unroll
      for (int j = 0; j < 4; ++j)
#pragma unroll
        for (int nt = 0; nt < 2; ++nt)
          acc[j][nt] = __builtin_amdgcn_mfma_f32_16x16x32_bf16(
              a, wf[j][nt][2 + kk], acc[j][nt], 0, 0, 0);
    }

    // ---- quiet pipelined poll for peer half of h_t ----
    if (t > 0) {
      bool ok = ((uint32)(v0 >> 32) == (uint32)t) &
                ((uint32)(v1 >> 32) == (uint32)t);
      int it = 0;
      while (!__all(ok) && ++it < SENT_CAP) {
        u64 n0 = 0, n1 = 0;
        if (!ok) {
          n0 = aload64(up0);
          n1 = aload64(up1);
        }
        __builtin_amdgcn_s_sleep(1);
        if (!ok) {
          v0 = n0; v1 = n1;
          ok = ((uint32)(v0 >> 32) == (uint32)t) &
               ((uint32)(v1 >> 32) == (uint32)t);
        }
      }
      // capture payloads into current read-buffer (peer cols, disjoint
      // from Phase A's own-col reads)
      *(uint32*)&h_lds[t & 1][pm0][pcol] = (uint32)v0;
      *(uint32*)&h_lds[t & 1][pm0 + 4][pcol] = (uint32)v1;
    }
    __syncthreads();  // MID: peer half of buf[t&1] ready

    // ---- Phase C: peer-half h MFMAs (the only compute on the serial
    // publish->detect cycle) ----
#pragma unroll
    for (int kk = 0; kk < 4; ++kk) {
      bf16x8 a = __builtin_bit_cast(
          bf16x8, *(const ushortx8*)(hrow + peerb + kk * 32 + lk * 8));
#pragma unroll
      for (int j = 0; j < 4; ++j)
#pragma unroll
        for (int nt = 0; nt < 2; ++nt)
          acc[j][nt] = __builtin_amdgcn_mfma_f32_16x16x32_bf16(
              a, wf[j][nt][6 + kk], acc[j][nt], 0, 0, 0);
    }

    // ---- in-register nonlinearity + c/h update; publish ASAP ----
    if (lk < 2) {
#pragma unroll
      for (int nt = 0; nt < 2; ++nt) {
        floatx4 iv, fv, gv, ov;
#pragma unroll
        for (int r = 0; r < 4; ++r) {
          iv[r] = fast_sig(acc[0][nt][r]);
          fv[r] = fast_sig(acc[1][nt][r]);
          gv[r] = fast_tanh(acc[2][nt][r]);
          ov[r] = fast_sig(acc[3][nt][r]);
        }
        floatx4 c = (nt == 0) ? c0 : c1;
        c = fv * c + iv * gv;
        if (nt == 0) c0 = c; else c1 = c;
#pragma unroll
        for (int r = 0; r < 4; ++r) {
          float hv = ov[r] * fast_tanh(c[r]);
          unsigned short hb = __builtin_bit_cast(unsigned short, (__bf16)hv);
          int pv = __shfl_xor((int)hb, 1);  // partner ln^1, same lk
          if ((ln & 1) == 0) {
            const int m = lk * 4 + r;
            uint32 dword = (uint32)hb | ((uint32)(unsigned short)pv << 16);
            u64 val = (u64)dword | ((u64)(uint32)(t + 1) << 32);
            const size_t uoff = obase + (size_t)m * 64 + opair + nt * 8;
            if (t == T_ - 1) {
              // final h -> clean region (never polled, never RMW'd)
              astore64(units + 2 * (size_t)UNITS_PER_PARITY + uoff, val);
            } else {
              astore64(
                  units + (size_t)((t + 1) & 1) * UNITS_PER_PARITY + uoff,
                  val);
              // own half -> next read-buffer
              *(uint32*)&h_lds[(t + 1) & 1][m][ocol + nt * 16 + ln] = dword;
            }
          }
        }
      }
    }
    __syncthreads();  // END: buf[(t+1)&1] own half ready for Phase A(t+1)
  }
}

// out[b] = dot(h_T[b], fc_w) + fc_b. Final h lives in the clean region at
// offset 2*UPP. Agent loads -> fresh across replays, no flush dependency.
__global__ void lstm_fc(const u64* __restrict__ units,
                        const float* __restrict__ fc_w,
                        const float* __restrict__ fc_b,
                        float* __restrict__ out) {
  const int b = threadIdx.x;
  const int g = b >> 3, m = b & 7;
  const u64* base =
      units + 2 * (size_t)UNITS_PER_PARITY + (size_t)g * UNITS_PER_GROUP;
  float sum = fc_b[0];
#pragma unroll 4
  for (int u = 0; u < 128; ++u) {
    const int hf = u >> 6, pair = u & 63;
    u64 v = aload64(base + hf * 512 + m * 64 + pair);
    uint32 lo = (uint32)v;
    const int d = hf * HH + 2 * pair;
    sum += bf2f(lo & 0xffffu) * fc_w[d] + bf2f(lo >> 16) * fc_w[d + 1];
  }
  out[b] = sum;
}

extern "C" void kernel_launch(void* const* d_in, const int* in_sizes, int n_in,
                              void* d_out, int out_size, void* d_ws,
                              size_t ws_size, hipStream_t stream) {
  const float* x    = (const float*)d_in[0];
  const float* W_ih = (const float*)d_in[1];
  const float* W_hh = (const float*)d_in[2];
  const float* b_ih = (const float*)d_in[3];
  const float* b_hh = (const float*)d_in[4];
  const float* fc_w = (const float*)d_in[5];
  const float* fc_b = (const float*)d_in[6];
  float* out = (float*)d_out;

  u64* units = (u64*)d_ws;  // 2 parities + final region: 3*256KB = 768KB ws
  // tag poison 0xAAAAAAAA != any live tag (1..1024) => no init needed.

  lstm_main<<<dim3(NGROUP * 2), dim3(256), 0, stream>>>(
      x, W_ih, W_hh, b_ih, b_hh, units);
  lstm_fc<<<dim3(1), dim3(256), 0, stream>>>(units, fc_w, fc_b, out);
}